// Round 10
// baseline (1663.709 us; speedup 1.0000x reference)
//
#include <hip/hip_runtime.h>

#define NL 6
#define EMB 384
#define NH 6
#define HSZ 64
#define TT 256
#define NTOK 4096
#define VOC 50257
#define VOCP 50304
#define FF 1536
#define QKVW 1152
#define NCH 393

typedef __attribute__((ext_vector_type(8))) short bf16x8;
typedef __attribute__((ext_vector_type(4))) float f32x4;

__device__ __forceinline__ short f2bf(float f) {
  unsigned u = __float_as_uint(f);
  u = (u + 0x7fffu + ((u >> 16) & 1u)) >> 16;
  return (short)u;
}

// involutive 16B-granular LDS swizzle: bits[5:4] ^= f(bits[8:6]); swz(swz(x)) == x
__device__ __forceinline__ int swz16(int b) {
  return b ^ (((((b >> 6) ^ (b >> 8)) & 1) << 4) | (((b >> 7) & 1) << 5));
}

__device__ __forceinline__ void gl16(const void* g, void* l) {
  __builtin_amdgcn_global_load_lds(
      (const __attribute__((address_space(1))) unsigned*)g,
      (__attribute__((address_space(3))) unsigned*)l, 16, 0, 0);
}

// ---------------- embedding ----------------
__global__ void embed_k(const int* __restrict__ idx, const float* __restrict__ tok,
                        const float* __restrict__ pos, float* __restrict__ x) {
  int row = blockIdx.x, col = threadIdx.x;
  int t = idx[row];
  x[(size_t)row * EMB + col] = tok[(size_t)t * EMB + col] + pos[(size_t)(row & 255) * EMB + col];
}

// ---------------- transpose + cast f32 -> bf16 : dst[n][k] = src[k][n] ----------------
__global__ __launch_bounds__(256) void tcast_k(const float* __restrict__ src, short* __restrict__ dst,
                                               int K, int N, long sstr, long dstr) {
  src += (size_t)blockIdx.z * sstr;
  dst += (size_t)blockIdx.z * dstr;
  __shared__ float tile[32][33];
  int lx = threadIdx.x & 31, ly = threadIdx.x >> 5;
  int k0 = blockIdx.y << 5, n0 = blockIdx.x << 5;
#pragma unroll
  for (int j = 0; j < 4; ++j) {
    int k = k0 + ly + (j << 3), n = n0 + lx;
    tile[ly + (j << 3)][lx] = (n < N) ? src[(size_t)k * N + n] : 0.f;
  }
  __syncthreads();
#pragma unroll
  for (int j = 0; j < 4; ++j) {
    int n = n0 + ly + (j << 3), k = k0 + lx;
    dst[(size_t)n * K + k] = f2bf(tile[lx][ly + (j << 3)]);
  }
}

// ---------------- layernorm (f32 in) -> bf16 out ----------------
__global__ __launch_bounds__(256) void ln_k(const float* __restrict__ x, const float* __restrict__ g,
                                            const float* __restrict__ b, short* __restrict__ out) {
  int wave = threadIdx.x >> 6, lane = threadIdx.x & 63;
  int row = (blockIdx.x << 2) + wave;
  const float* p = x + (size_t)row * EMB;
  float v[6]; float s = 0.f;
#pragma unroll
  for (int j = 0; j < 6; ++j) { v[j] = p[lane + (j << 6)]; s += v[j]; }
#pragma unroll
  for (int o = 32; o; o >>= 1) s += __shfl_xor(s, o, 64);
  float mu = s * (1.f / EMB);
  float q = 0.f;
#pragma unroll
  for (int j = 0; j < 6; ++j) { float d = v[j] - mu; q += d * d; }
#pragma unroll
  for (int o = 32; o; o >>= 1) q += __shfl_xor(q, o, 64);
  float rstd = rsqrtf(q * (1.f / EMB) + 1e-5f);
  short* op = out + (size_t)row * EMB;
#pragma unroll
  for (int j = 0; j < 6; ++j) {
    int c = lane + (j << 6);
    op[c] = f2bf((v[j] - mu) * rstd * g[c] + b[c]);
  }
}

// ---------------- fused attention: scores + causal softmax + PV (causal-trimmed) ------------
template <int KFB>
__device__ __forceinline__ void attn_body(const short* __restrict__ qkv,
                                          const short* __restrict__ vt,
                                          short* __restrict__ att,
                                          short (*P)[260], int qt, int bh, int tid) {
  const float SCALE = 0.051031036307982884f;  // 1/sqrt(384)
  int b = bh / NH, h = bh % NH;
  int w = tid >> 6, lane = tid & 63;
  int lr = lane & 15, g = lane >> 4;
  int qbase = qt * 64 + w * 16;

  const short* qrow = qkv + (size_t)(b * TT + qbase + lr) * QKVW + h * HSZ;
  bf16x8 qa0 = *(const bf16x8*)(qrow + g * 8);
  bf16x8 qa1 = *(const bf16x8*)(qrow + 32 + g * 8);

  f32x4 zero = {0.f, 0.f, 0.f, 0.f};
  f32x4 s[KFB];
#pragma unroll
  for (int kf = 0; kf < KFB; ++kf) s[kf] = zero;
#pragma unroll
  for (int kf = 0; kf < KFB; ++kf) {
    const short* krow = qkv + (size_t)(b * TT + kf * 16 + lr) * QKVW + EMB + h * HSZ;
    bf16x8 kb0 = *(const bf16x8*)(krow + g * 8);
    bf16x8 kb1 = *(const bf16x8*)(krow + 32 + g * 8);
    s[kf] = __builtin_amdgcn_mfma_f32_16x16x32_bf16(qa0, kb0, s[kf], 0, 0, 0);
    s[kf] = __builtin_amdgcn_mfma_f32_16x16x32_bf16(qa1, kb1, s[kf], 0, 0, 0);
  }

#pragma unroll
  for (int i = 0; i < 4; ++i) {
    int qg = qbase + g * 4 + i;
    float m = -1e30f;
#pragma unroll
    for (int kf = 0; kf < KFB; ++kf) {
      float v = s[kf][i] * SCALE;
      if (kf * 16 + lr > qg) v = -1e30f;
      s[kf][i] = v;
      m = fmaxf(m, v);
    }
#pragma unroll
    for (int o = 8; o; o >>= 1) m = fmaxf(m, __shfl_xor(m, o, 64));
    float sum = 0.f;
#pragma unroll
    for (int kf = 0; kf < KFB; ++kf) {
      float e = __expf(s[kf][i] - m);
      s[kf][i] = e;
      sum += e;
    }
#pragma unroll
    for (int o = 8; o; o >>= 1) sum += __shfl_xor(sum, o, 64);
    float inv = 1.f / sum;
#pragma unroll
    for (int kf = 0; kf < KFB; ++kf)
      P[w * 16 + g * 4 + i][kf * 16 + lr] = f2bf(s[kf][i] * inv);
  }

  f32x4 o4[4];
#pragma unroll
  for (int nf = 0; nf < 4; ++nf) o4[nf] = zero;
  const short* vbase = vt + (size_t)bh * 64 * TT;
#pragma unroll
  for (int ks = 0; ks < KFB / 2; ++ks) {
    bf16x8 pa = *(const bf16x8*)&P[w * 16 + lr][ks * 32 + g * 8];
#pragma unroll
    for (int nf = 0; nf < 4; ++nf) {
      bf16x8 vb = *(const bf16x8*)(vbase + (size_t)(nf * 16 + lr) * TT + ks * 32 + g * 8);
      o4[nf] = __builtin_amdgcn_mfma_f32_16x16x32_bf16(pa, vb, o4[nf], 0, 0, 0);
    }
  }
#pragma unroll
  for (int nf = 0; nf < 4; ++nf)
#pragma unroll
    for (int i = 0; i < 4; ++i)
      att[(size_t)(b * TT + qbase + g * 4 + i) * EMB + h * HSZ + nf * 16 + lr] = f2bf(o4[nf][i]);
}

__global__ __launch_bounds__(256) void attn_k(const short* __restrict__ qkv,
                                              const short* __restrict__ vt,
                                              short* __restrict__ att) {
  __shared__ short P[64][260];
  int qt = blockIdx.x, bh = blockIdx.y, tid = threadIdx.x;
  if (qt == 0)      attn_body<4>(qkv, vt, att, P, 0, bh, tid);
  else if (qt == 1) attn_body<8>(qkv, vt, att, P, 1, bh, tid);
  else if (qt == 2) attn_body<12>(qkv, vt, att, P, 2, bh, tid);
  else              attn_body<16>(qkv, vt, att, P, 3, bh, tid);
}

// ---------------- generic 128x128 MFMA GEMM: C = A[M,K] * Bt[N,K]^T ----------------
#define GM_QKV 0
#define GM_RESID 3
#define GM_FC1 4

template <int MODE>
__global__ __launch_bounds__(256) void gemm_k(
    const short* __restrict__ Ag, const short* __restrict__ Btg, void* Cg,
    const float* __restrict__ bias, const float* resid,
    int K, int lda, int ldb, int ldc, short* __restrict__ vtp) {
  __shared__ alignas(1024) short sA[2 * 128 * 32];
  __shared__ alignas(1024) short sB[2 * 128 * 32];
  int tid = threadIdx.x;
  int bm = blockIdx.x, bn = blockIdx.y;
  int wave = tid >> 6, lane = tid & 63;
  int wm = wave >> 1, wn = wave & 1;
  int lr = lane & 15, kq = lane >> 4;
  size_t lda2 = (size_t)lda * 2, ldb2 = (size_t)ldb * 2;

  int p = wave * 1024 + lane * 16;
  int q = swz16(p);
  int srow = q >> 6, scb = q & 63;
  const char* gA = (const char*)Ag + (size_t)(bm * 128 + srow) * lda2 + scb;
  const char* gB = (const char*)Btg + (size_t)(bn * 128 + srow) * ldb2 + scb;
  char* lA0 = (char*)sA + wave * 1024; char* lA1 = lA0 + 4096;
  char* lB0 = (char*)sB + wave * 1024; char* lB1 = lB0 + 4096;

  const char* apf[4]; const char* bpf[4];
#pragma unroll
  for (int f = 0; f < 4; ++f) {
    int La = (wm * 64 + f * 16 + lr) * 64 + kq * 16;
    apf[f] = (const char*)sA + swz16(La);
    int Lb = (wn * 64 + f * 16 + lr) * 64 + kq * 16;
    bpf[f] = (const char*)sB + swz16(Lb);
  }

  f32x4 zero = {0.f, 0.f, 0.f, 0.f};
  f32x4 acc[4][4];
#pragma unroll
  for (int i = 0; i < 4; ++i)
#pragma unroll
    for (int j = 0; j < 4; ++j) acc[i][j] = zero;

  auto STAGE = [&](int t, int bufoff) {
    const char* ga2 = gA + (size_t)t * 64;
    const char* gb2 = gB + (size_t)t * 64;
    gl16(ga2, lA0 + bufoff); gl16(ga2 + 64 * lda2, lA1 + bufoff);
    gl16(gb2, lB0 + bufoff); gl16(gb2 + 64 * ldb2, lB1 + bufoff);
  };

  int nt = K >> 5;
  STAGE(0, 0);
  STAGE(1, 8192);
  for (int t = 0; t < nt; ++t) {
    int cur = (t & 1) << 13;
    if (t + 1 < nt) { asm volatile("s_waitcnt vmcnt(4)\ns_barrier" ::: "memory"); }
    else            { asm volatile("s_waitcnt vmcnt(0)\ns_barrier" ::: "memory"); }
    bf16x8 af[4], bfr[4];
#pragma unroll
    for (int f = 0; f < 4; ++f) {
      af[f] = *(const bf16x8*)(apf[f] + cur);
      bfr[f] = *(const bf16x8*)(bpf[f] + cur);
    }
#pragma unroll
    for (int i = 0; i < 4; ++i)
#pragma unroll
      for (int j = 0; j < 4; ++j)
        acc[i][j] = __builtin_amdgcn_mfma_f32_16x16x32_bf16(af[i], bfr[j], acc[i][j], 0, 0, 0);
    asm volatile("s_waitcnt lgkmcnt(0)\ns_barrier" ::: "memory");
    if (t + 2 < nt) STAGE(t + 2, cur);
  }

  int row0 = bm * 128 + wm * 64 + (kq << 2);
  int col0 = bn * 128 + wn * 64 + lr;

  if constexpr (MODE == GM_QKV) {
    short* C = (short*)Cg;
#pragma unroll
    for (int fm = 0; fm < 4; ++fm)
#pragma unroll
      for (int fn = 0; fn < 4; ++fn) {
        int c = col0 + fn * 16;
#pragma unroll
        for (int i = 0; i < 4; ++i) {
          int r = row0 + fm * 16 + i;
          short val = f2bf(acc[fm][fn][i]);
          C[(size_t)r * ldc + c] = val;
          if (c >= 2 * EMB) {  // V columns: also write transposed copy vt[bh][d][t]
            int dg = c - 2 * EMB;
            int h = dg >> 6, d = dg & 63;
            int b = r >> 8, tt = r & 255;
            vtp[(((size_t)(b * NH + h) * 64 + d) << 8) + tt] = val;
          }
        }
      }
  } else if constexpr (MODE == GM_FC1) {
    short* C = (short*)Cg;
#pragma unroll
    for (int fm = 0; fm < 4; ++fm)
#pragma unroll
      for (int fn = 0; fn < 4; ++fn) {
        int c = col0 + fn * 16;
        float bv = bias[c];
#pragma unroll
        for (int i = 0; i < 4; ++i)
          C[(size_t)(row0 + fm * 16 + i) * ldc + c] = f2bf(fmaxf(acc[fm][fn][i] + bv, 0.f));
      }
  } else if constexpr (MODE == GM_RESID) {
    float* C = (float*)Cg;
#pragma unroll
    for (int fm = 0; fm < 4; ++fm)
#pragma unroll
      for (int fn = 0; fn < 4; ++fn) {
        int c = col0 + fn * 16;
        float bv = bias[c];
#pragma unroll
        for (int i = 0; i < 4; ++i) {
          size_t o = (size_t)(row0 + fm * 16 + i) * ldc + c;
          C[o] = resid[o] + acc[fm][fn][i] + bv;
        }
      }
  }
}

// ---------------- head GEMM: A via small LDS, B direct-from-global (L2-hot), fused LSE ------
__global__ __launch_bounds__(256, 4) void head_k(const short* __restrict__ Ag,
                                                 const short* __restrict__ Btg,
                                                 float* __restrict__ C,
                                                 const float* __restrict__ bias,
                                                 float* __restrict__ pm, float* __restrict__ ps) {
  __shared__ alignas(1024) short sA[128 * 32];  // 8 KB single buffer
  __shared__ float redm[2][2][64];
  __shared__ float reds[2][2][64];
  int tid = threadIdx.x;
  int bm = blockIdx.x, bn = blockIdx.y;
  int wave = tid >> 6, lane = tid & 63;
  int wm = wave >> 1, wn = wave & 1;
  int lr = lane & 15, kq = lane >> 4;
  const size_t lda2 = EMB * 2;

  int p = wave * 1024 + lane * 16;
  int q = swz16(p);
  int srow = q >> 6, scb = q & 63;
  const char* gA = (const char*)Ag + (size_t)(bm * 128 + srow) * lda2 + scb;
  char* lA0 = (char*)sA + wave * 1024; char* lA1 = lA0 + 4096;

  const char* apf[4];
#pragma unroll
  for (int f = 0; f < 4; ++f)
    apf[f] = (const char*)sA + swz16((wm * 64 + f * 16 + lr) * 64 + kq * 16);

  // B row pointers (rows < VOCP padded, always valid)
  const short* bp[4];
#pragma unroll
  for (int f = 0; f < 4; ++f)
    bp[f] = Btg + (size_t)(bn * 128 + wn * 64 + f * 16 + lr) * EMB + kq * 8;

  f32x4 zero = {0.f, 0.f, 0.f, 0.f};
  f32x4 acc[4][4];
#pragma unroll
  for (int i = 0; i < 4; ++i)
#pragma unroll
    for (int j = 0; j < 4; ++j) acc[i][j] = zero;

  // prefetch B(0)
  bf16x8 bcur[4];
#pragma unroll
  for (int f = 0; f < 4; ++f) bcur[f] = *(const bf16x8*)(bp[f]);

  const int NT = EMB / 32;  // 12
  for (int t = 0; t < NT; ++t) {
    __syncthreads();  // all waves done reading sA from previous step
    gl16(gA + (size_t)t * 64, lA0);
    gl16(gA + (size_t)t * 64 + 64 * lda2, lA1);
    bf16x8 bnxt[4];
    if (t + 1 < NT) {
#pragma unroll
      for (int f = 0; f < 4; ++f) bnxt[f] = *(const bf16x8*)(bp[f] + (t + 1) * 32);
    }
    __syncthreads();  // A(t) in LDS (implicit vmcnt0); B(t+1) latency hidden here
    bf16x8 af[4];
#pragma unroll
    for (int f = 0; f < 4; ++f) af[f] = *(const bf16x8*)(apf[f]);
#pragma unroll
    for (int i = 0; i < 4; ++i)
#pragma unroll
      for (int j = 0; j < 4; ++j)
        acc[i][j] = __builtin_amdgcn_mfma_f32_16x16x32_bf16(af[i], bcur[j], acc[i][j], 0, 0, 0);
#pragma unroll
    for (int f = 0; f < 4; ++f) bcur[f] = bnxt[f];
  }

  int row0 = bm * 128 + wm * 64 + (kq << 2);
  int col0 = bn * 128 + wn * 64 + lr;

  bool okv[4]; float bv[4];
#pragma unroll
  for (int fn = 0; fn < 4; ++fn) {
    int c = col0 + fn * 16;
    okv[fn] = c < VOC;
    bv[fn] = okv[fn] ? bias[c] : 0.f;
  }
#pragma unroll
  for (int fm = 0; fm < 4; ++fm)
#pragma unroll
    for (int fn = 0; fn < 4; ++fn)
#pragma unroll
      for (int i = 0; i < 4; ++i) acc[fm][fn][i] += bv[fn];

  // per-row LSE partial (max then sum; 16 lanes per row)
#pragma unroll
  for (int fm = 0; fm < 4; ++fm)
#pragma unroll
    for (int i = 0; i < 4; ++i) {
      float v0 = okv[0] ? acc[fm][0][i] : -1e30f;
      float v1 = okv[1] ? acc[fm][1][i] : -1e30f;
      float v2 = okv[2] ? acc[fm][2][i] : -1e30f;
      float v3 = okv[3] ? acc[fm][3][i] : -1e30f;
      float mx = fmaxf(fmaxf(v0, v1), fmaxf(v2, v3));
#pragma unroll
      for (int o = 8; o; o >>= 1) mx = fmaxf(mx, __shfl_xor(mx, o, 64));
      float sm = __expf(v0 - mx) + __expf(v1 - mx) + __expf(v2 - mx) + __expf(v3 - mx);
#pragma unroll
      for (int o = 8; o; o >>= 1) sm += __shfl_xor(sm, o, 64);
      if (lr == 0) {
        int rl = fm * 16 + (kq << 2) + i;
        redm[wm][wn][rl] = mx; reds[wm][wn][rl] = sm;
      }
    }
  __syncthreads();
  if (tid < 128) {
    int wmm = tid >> 6, rl = tid & 63;
    float m0 = redm[wmm][0][rl], m1 = redm[wmm][1][rl];
    float s0 = reds[wmm][0][rl], s1 = reds[wmm][1][rl];
    float M = fmaxf(m0, m1);
    float S = s0 * __expf(m0 - M) + s1 * __expf(m1 - M);
    int r = bm * 128 + wmm * 64 + rl;
    pm[(size_t)r * NCH + bn] = M;
    ps[(size_t)r * NCH + bn] = S;
  }

  // direct stores: 16 consecutive lanes cover 64B sectors fully -> nt safe
#pragma unroll
  for (int fm = 0; fm < 4; ++fm)
#pragma unroll
    for (int fn = 0; fn < 4; ++fn) {
      if (!okv[fn]) continue;
      int c = col0 + fn * 16;
#pragma unroll
      for (int i = 0; i < 4; ++i) {
        int r = row0 + fm * 16 + i;
        __builtin_nontemporal_store(acc[fm][fn][i], &C[(size_t)r * VOC + c]);
      }
    }
}

// ---------------- combine per-chunk LSE partials -> per-row loss ----------------
__global__ __launch_bounds__(256) void lsecomb_k(const float* __restrict__ pm, const float* __restrict__ ps,
                                                 const float* __restrict__ logits, const int* __restrict__ tgt,
                                                 float* __restrict__ rowloss) {
  int wave = threadIdx.x >> 6, lane = threadIdx.x & 63;
  int r = (blockIdx.x << 2) + wave;
  float m = -1e30f, s = 0.f;
  for (int i = lane; i < NCH; i += 64) {
    float bm = pm[(size_t)r * NCH + i], bs = ps[(size_t)r * NCH + i];
    float M = fmaxf(m, bm);
    s = s * __expf(m - M) + bs * __expf(bm - M);
    m = M;
  }
#pragma unroll
  for (int o = 32; o; o >>= 1) {
    float mo = __shfl_xor(m, o, 64), so = __shfl_xor(s, o, 64);
    float M = fmaxf(m, mo);
    s = s * __expf(m - M) + so * __expf(mo - M);
    m = M;
  }
  if (lane == 0) rowloss[r] = m + __logf(s) - logits[(size_t)r * VOC + tgt[r]];
}

__global__ __launch_bounds__(256) void loss_final_k(const float* __restrict__ rowloss,
                                                    float* __restrict__ out) {
  __shared__ float sb[256];
  int tid = threadIdx.x;
  float s = 0.f;
  for (int i = tid; i < NTOK; i += 256) s += rowloss[i];
  sb[tid] = s;
  __syncthreads();
  for (int o = 128; o; o >>= 1) {
    if (tid < o) sb[tid] += sb[tid + o];
    __syncthreads();
  }
  if (tid == 0) out[0] = sb[0] * (1.f / NTOK);
}

extern "C" void kernel_launch(void* const* d_in, const int* in_sizes, int n_in,
                              void* d_out, int out_size, void* d_ws, size_t ws_size,
                              hipStream_t stream) {
  const int* idx = (const int*)d_in[0];
  const int* tgt = (const int*)d_in[1];
  const float* tok = (const float*)d_in[2];
  const float* pos = (const float*)d_in[3];
  const float* Wq = (const float*)d_in[4];
  const float* Wk = (const float*)d_in[5];
  const float* Wv = (const float*)d_in[6];
  const float* Wp = (const float*)d_in[7];
  const float* bp = (const float*)d_in[8];
  const float* W1 = (const float*)d_in[9];
  const float* b1 = (const float*)d_in[10];
  const float* W2 = (const float*)d_in[11];
  const float* b2 = (const float*)d_in[12];
  const float* ln1g = (const float*)d_in[13];
  const float* ln1b = (const float*)d_in[14];
  const float* ln2g = (const float*)d_in[15];
  const float* ln2b = (const float*)d_in[16];
  const float* lnfg = (const float*)d_in[17];
  const float* lnfb = (const float*)d_in[18];
  const float* Wh = (const float*)d_in[19];
  const float* bh = (const float*)d_in[20];

  char* wp = (char*)d_ws;
  auto take = [&](size_t elems, size_t esz) {
    void* r = (void*)wp;
    wp += (elems * esz + 255) & ~(size_t)255;
    return r;
  };
  short* wqkv_t = (short*)take((size_t)NL * QKVW * EMB, 2);
  short* wproj_t = (short*)take((size_t)NL * EMB * EMB, 2);
  short* w1_t = (short*)take((size_t)NL * FF * EMB, 2);
  short* w2_t = (short*)take((size_t)NL * EMB * FF, 2);
  short* whead_t = (short*)take((size_t)VOCP * EMB, 2);
  float* x = (float*)take((size_t)NTOK * EMB, 4);
  short* hb = (short*)take((size_t)NTOK * EMB, 2);
  short* qkv = (short*)take((size_t)NTOK * QKVW, 2);
  float* sc = (float*)take((size_t)96 * TT * TT, 4);
  short* vt = (short*)take((size_t)96 * 64 * TT, 2);
  short* att = (short*)take((size_t)NTOK * EMB, 2);
  short* f1 = (short*)take((size_t)NTOK * FF, 2);
  float* rl = (float*)take((size_t)NTOK, 4);

  float* pm = sc;
  float* ps = sc + (size_t)NTOK * NCH;

  tcast_k<<<dim3(12, 12, NL), 256, 0, stream>>>(Wq, wqkv_t, EMB, EMB, (long)EMB * EMB, (long)QKVW * EMB);
  tcast_k<<<dim3(12, 12, NL), 256, 0, stream>>>(Wk, wqkv_t + EMB * EMB, EMB, EMB, (long)EMB * EMB, (long)QKVW * EMB);
  tcast_k<<<dim3(12, 12, NL), 256, 0, stream>>>(Wv, wqkv_t + 2 * EMB * EMB, EMB, EMB, (long)EMB * EMB, (long)QKVW * EMB);
  tcast_k<<<dim3(12, 12, NL), 256, 0, stream>>>(Wp, wproj_t, EMB, EMB, (long)EMB * EMB, (long)EMB * EMB);
  tcast_k<<<dim3(48, 12, NL), 256, 0, stream>>>(W1, w1_t, EMB, FF, (long)EMB * FF, (long)FF * EMB);
  tcast_k<<<dim3(12, 48, NL), 256, 0, stream>>>(W2, w2_t, FF, EMB, (long)FF * EMB, (long)EMB * FF);
  tcast_k<<<dim3(VOCP / 32, 12, 1), 256, 0, stream>>>(Wh, whead_t, EMB, VOC, 0, 0);

  embed_k<<<NTOK, EMB, 0, stream>>>(idx, tok, pos, x);

  for (int l = 0; l < NL; ++l) {
    ln_k<<<NTOK / 4, 256, 0, stream>>>(x, ln1g + l * EMB, ln1b + l * EMB, hb);
    gemm_k<GM_QKV><<<dim3(32, 9), 256, 0, stream>>>(hb, wqkv_t + (size_t)l * QKVW * EMB, qkv,
        nullptr, nullptr, EMB, EMB, EMB, QKVW, vt);
    attn_k<<<dim3(4, 96), 256, 0, stream>>>(qkv, vt, att);
    gemm_k<GM_RESID><<<dim3(32, 3), 256, 0, stream>>>(att, wproj_t + (size_t)l * EMB * EMB, x,
        bp + l * EMB, x, EMB, EMB, EMB, EMB, nullptr);
    ln_k<<<NTOK / 4, 256, 0, stream>>>(x, ln2g + l * EMB, ln2b + l * EMB, hb);
    gemm_k<GM_FC1><<<dim3(32, 12), 256, 0, stream>>>(hb, w1_t + (size_t)l * FF * EMB, f1,
        b1 + l * FF, nullptr, EMB, EMB, EMB, FF, nullptr);
    gemm_k<GM_RESID><<<dim3(32, 3), 256, 0, stream>>>(f1, w2_t + (size_t)l * EMB * FF, x,
        b2 + l * EMB, x, FF, FF, FF, EMB, nullptr);
  }

  ln_k<<<NTOK / 4, 256, 0, stream>>>(x, lnfg, lnfb, hb);
  head_k<<<dim3(32, NCH), 256, 0, stream>>>(hb, whead_t, (float*)d_out, bh, pm, ps);
  lsecomb_k<<<NTOK / 4, 256, 0, stream>>>(pm, ps, (const float*)d_out, tgt, rl);
  loss_final_k<<<1, 256, 0, stream>>>(rl, (float*)d_out + (size_t)NTOK * VOC);
}

// Round 11
// 1170.705 us; speedup vs baseline: 1.4211x; 1.4211x over previous
//
#include <hip/hip_runtime.h>

#define NL 6
#define EMB 384
#define NH 6
#define HSZ 64
#define TT 256
#define NTOK 4096
#define VOC 50257
#define VOCP 50304
#define FF 1536
#define QKVW 1152
#define NCH 393

typedef __attribute__((ext_vector_type(8))) short bf16x8;
typedef __attribute__((ext_vector_type(4))) float f32x4;

__device__ __forceinline__ short f2bf(float f) {
  unsigned u = __float_as_uint(f);
  u = (u + 0x7fffu + ((u >> 16) & 1u)) >> 16;
  return (short)u;
}

// involutive 16B-granular LDS swizzle: bits[5:4] ^= f(bits[8:6]); swz(swz(x)) == x
__device__ __forceinline__ int swz16(int b) {
  return b ^ (((((b >> 6) ^ (b >> 8)) & 1) << 4) | (((b >> 7) & 1) << 5));
}

__device__ __forceinline__ void gl16(const void* g, void* l) {
  __builtin_amdgcn_global_load_lds(
      (const __attribute__((address_space(1))) unsigned*)g,
      (__attribute__((address_space(3))) unsigned*)l, 16, 0, 0);
}

// ---------------- embedding ----------------
__global__ void embed_k(const int* __restrict__ idx, const float* __restrict__ tok,
                        const float* __restrict__ pos, float* __restrict__ x) {
  int row = blockIdx.x, col = threadIdx.x;
  int t = idx[row];
  x[(size_t)row * EMB + col] = tok[(size_t)t * EMB + col] + pos[(size_t)(row & 255) * EMB + col];
}

// ---------------- transpose + cast f32 -> bf16 : dst[n][k] = src[k][n] ----------------
__global__ __launch_bounds__(256) void tcast_k(const float* __restrict__ src, short* __restrict__ dst,
                                               int K, int N, long sstr, long dstr) {
  src += (size_t)blockIdx.z * sstr;
  dst += (size_t)blockIdx.z * dstr;
  __shared__ float tile[32][33];
  int lx = threadIdx.x & 31, ly = threadIdx.x >> 5;
  int k0 = blockIdx.y << 5, n0 = blockIdx.x << 5;
#pragma unroll
  for (int j = 0; j < 4; ++j) {
    int k = k0 + ly + (j << 3), n = n0 + lx;
    tile[ly + (j << 3)][lx] = (n < N) ? src[(size_t)k * N + n] : 0.f;
  }
  __syncthreads();
#pragma unroll
  for (int j = 0; j < 4; ++j) {
    int n = n0 + ly + (j << 3), k = k0 + lx;
    dst[(size_t)n * K + k] = f2bf(tile[lx][ly + (j << 3)]);
  }
}

// ---------------- layernorm (f32 in) -> bf16 out ----------------
__global__ __launch_bounds__(256) void ln_k(const float* __restrict__ x, const float* __restrict__ g,
                                            const float* __restrict__ b, short* __restrict__ out) {
  int wave = threadIdx.x >> 6, lane = threadIdx.x & 63;
  int row = (blockIdx.x << 2) + wave;
  const float* p = x + (size_t)row * EMB;
  float v[6]; float s = 0.f;
#pragma unroll
  for (int j = 0; j < 6; ++j) { v[j] = p[lane + (j << 6)]; s += v[j]; }
#pragma unroll
  for (int o = 32; o; o >>= 1) s += __shfl_xor(s, o, 64);
  float mu = s * (1.f / EMB);
  float q = 0.f;
#pragma unroll
  for (int j = 0; j < 6; ++j) { float d = v[j] - mu; q += d * d; }
#pragma unroll
  for (int o = 32; o; o >>= 1) q += __shfl_xor(q, o, 64);
  float rstd = rsqrtf(q * (1.f / EMB) + 1e-5f);
  short* op = out + (size_t)row * EMB;
#pragma unroll
  for (int j = 0; j < 6; ++j) {
    int c = lane + (j << 6);
    op[c] = f2bf((v[j] - mu) * rstd * g[c] + b[c]);
  }
}

// ---------------- V transpose: qkv -> vt[bh][d][t], d<64 ----------------
__global__ __launch_bounds__(256) void vtrans_k(const short* __restrict__ qkv, short* __restrict__ vt) {
  int bh = blockIdx.y; int b = bh / NH, h = bh % NH;
  int t0 = blockIdx.x << 6;
  __shared__ short tile[64][72];
  int tid = threadIdx.x;
#pragma unroll
  for (int pass = 0; pass < 2; ++pass) {
    int tl = pass * 32 + (tid >> 3);
    int d0 = (tid & 7) << 3;
    uint4 v = *(const uint4*)&qkv[((size_t)(b * TT + t0 + tl)) * QKVW + 2 * EMB + h * HSZ + d0];
    *(uint4*)&tile[tl][d0] = v;
  }
  __syncthreads();
  int d = tid >> 2, tc = (tid & 3) << 4;
  short* dst = &vt[((size_t)bh * 64 + d) * TT + t0 + tc];
#pragma unroll
  for (int j = 0; j < 16; ++j) dst[j] = tile[tc + j][d];
}

// ---------------- fused attention: scores + causal softmax + PV ----------------
__global__ __launch_bounds__(256) void attn_k(const short* __restrict__ qkv,
                                              const short* __restrict__ vt,
                                              short* __restrict__ att) {
  const float SCALE = 0.051031036307982884f;  // 1/sqrt(384)
  int qt = blockIdx.x, bh = blockIdx.y;
  int b = bh / NH, h = bh % NH;
  __shared__ short P[64][260];
  int tid = threadIdx.x, w = tid >> 6, lane = tid & 63;
  int lr = lane & 15, g = lane >> 4;
  int qbase = qt * 64 + w * 16;

  const short* qrow = qkv + (size_t)(b * TT + qbase + lr) * QKVW + h * HSZ;
  bf16x8 qa0 = *(const bf16x8*)(qrow + g * 8);
  bf16x8 qa1 = *(const bf16x8*)(qrow + 32 + g * 8);

  f32x4 zero = {0.f, 0.f, 0.f, 0.f};
  f32x4 s[16];
#pragma unroll
  for (int kf = 0; kf < 16; ++kf) s[kf] = zero;
#pragma unroll
  for (int kf = 0; kf < 16; ++kf) {
    const short* krow = qkv + (size_t)(b * TT + kf * 16 + lr) * QKVW + EMB + h * HSZ;
    bf16x8 kb0 = *(const bf16x8*)(krow + g * 8);
    bf16x8 kb1 = *(const bf16x8*)(krow + 32 + g * 8);
    s[kf] = __builtin_amdgcn_mfma_f32_16x16x32_bf16(qa0, kb0, s[kf], 0, 0, 0);
    s[kf] = __builtin_amdgcn_mfma_f32_16x16x32_bf16(qa1, kb1, s[kf], 0, 0, 0);
  }

#pragma unroll
  for (int i = 0; i < 4; ++i) {
    int qg = qbase + g * 4 + i;
    float m = -1e30f;
#pragma unroll
    for (int kf = 0; kf < 16; ++kf) {
      float v = s[kf][i] * SCALE;
      if (kf * 16 + lr > qg) v = -1e30f;
      s[kf][i] = v;
      m = fmaxf(m, v);
    }
#pragma unroll
    for (int o = 8; o; o >>= 1) m = fmaxf(m, __shfl_xor(m, o, 64));
    float sum = 0.f;
#pragma unroll
    for (int kf = 0; kf < 16; ++kf) {
      float e = __expf(s[kf][i] - m);
      s[kf][i] = e;
      sum += e;
    }
#pragma unroll
    for (int o = 8; o; o >>= 1) sum += __shfl_xor(sum, o, 64);
    float inv = 1.f / sum;
#pragma unroll
    for (int kf = 0; kf < 16; ++kf)
      P[w * 16 + g * 4 + i][kf * 16 + lr] = f2bf(s[kf][i] * inv);
  }

  f32x4 o4[4];
#pragma unroll
  for (int nf = 0; nf < 4; ++nf) o4[nf] = zero;
  const short* vbase = vt + (size_t)bh * 64 * TT;
#pragma unroll
  for (int ks = 0; ks < 8; ++ks) {
    bf16x8 pa = *(const bf16x8*)&P[w * 16 + lr][ks * 32 + g * 8];
#pragma unroll
    for (int nf = 0; nf < 4; ++nf) {
      bf16x8 vb = *(const bf16x8*)(vbase + (size_t)(nf * 16 + lr) * TT + ks * 32 + g * 8);
      o4[nf] = __builtin_amdgcn_mfma_f32_16x16x32_bf16(pa, vb, o4[nf], 0, 0, 0);
    }
  }
#pragma unroll
  for (int nf = 0; nf < 4; ++nf)
#pragma unroll
    for (int i = 0; i < 4; ++i)
      att[(size_t)(b * TT + qbase + g * 4 + i) * EMB + h * HSZ + nf * 16 + lr] = f2bf(o4[nf][i]);
}

// ---------------- generic 128x128 MFMA GEMM: C = A[M,K] * Bt[N,K]^T ----------------
#define GM_QKV 0
#define GM_RESID 3
#define GM_FC1 4
#define GM_HEAD 5

template <int MODE>
__global__ __launch_bounds__(256) void gemm_k(
    const short* __restrict__ Ag, const short* __restrict__ Btg, void* Cg,
    const float* __restrict__ bias, const float* resid,
    int K, int lda, int ldb, int ldc, float scale,
    float* __restrict__ pm, float* __restrict__ ps) {
  __shared__ alignas(1024) char smem[2 * 2 * 128 * 32 * 2];  // sA dbuf + sB dbuf (32 KB)
  short* sA = (short*)smem;
  short* sB = (short*)(smem + 16384);
  int tid = threadIdx.x;
  int bm = blockIdx.x, bn = blockIdx.y;
  int wave = tid >> 6, lane = tid & 63;
  int wm = wave >> 1, wn = wave & 1;
  int lr = lane & 15, kq = lane >> 4;
  size_t lda2 = (size_t)lda * 2, ldb2 = (size_t)ldb * 2;

  int p = wave * 1024 + lane * 16;
  int q = swz16(p);
  int srow = q >> 6, scb = q & 63;
  const char* gA = (const char*)Ag + (size_t)(bm * 128 + srow) * lda2 + scb;
  const char* gB = (const char*)Btg + (size_t)(bn * 128 + srow) * ldb2 + scb;
  char* lA0 = (char*)sA + wave * 1024; char* lA1 = lA0 + 4096;
  char* lB0 = (char*)sB + wave * 1024; char* lB1 = lB0 + 4096;

  const char* apf[4]; const char* bpf[4];
#pragma unroll
  for (int f = 0; f < 4; ++f) {
    int La = (wm * 64 + f * 16 + lr) * 64 + kq * 16;
    apf[f] = (const char*)sA + swz16(La);
    int Lb = (wn * 64 + f * 16 + lr) * 64 + kq * 16;
    bpf[f] = (const char*)sB + swz16(Lb);
  }

  f32x4 zero = {0.f, 0.f, 0.f, 0.f};
  f32x4 acc[4][4];
#pragma unroll
  for (int i = 0; i < 4; ++i)
#pragma unroll
    for (int j = 0; j < 4; ++j) acc[i][j] = zero;

  // prologue: stage k-step 0 into buf0
  gl16(gA, lA0); gl16(gA + 64 * lda2, lA1);
  gl16(gB, lB0); gl16(gB + 64 * ldb2, lB1);
  __syncthreads();

  int nt = K >> 5;
  for (int t = 0; t < nt; ++t) {
    int cur = (t & 1) << 13, nxt = (~t & 1) << 13;
    if (t + 1 < nt) {
      const char* ga2 = gA + (size_t)(t + 1) * 64;
      const char* gb2 = gB + (size_t)(t + 1) * 64;
      gl16(ga2, lA0 + nxt); gl16(ga2 + 64 * lda2, lA1 + nxt);
      gl16(gb2, lB0 + nxt); gl16(gb2 + 64 * ldb2, lB1 + nxt);
    }
    bf16x8 af[4], bfr[4];
#pragma unroll
    for (int f = 0; f < 4; ++f) {
      af[f] = *(const bf16x8*)(apf[f] + cur);
      bfr[f] = *(const bf16x8*)(bpf[f] + cur);
    }
#pragma unroll
    for (int i = 0; i < 4; ++i)
#pragma unroll
      for (int j = 0; j < 4; ++j)
        acc[i][j] = __builtin_amdgcn_mfma_f32_16x16x32_bf16(af[i], bfr[j], acc[i][j], 0, 0, 0);
    __syncthreads();
  }

  int row0 = bm * 128 + wm * 64 + (kq << 2);
  int col0 = bn * 128 + wn * 64 + lr;

  if constexpr (MODE == GM_QKV) {
    short* C = (short*)Cg;
#pragma unroll
    for (int fm = 0; fm < 4; ++fm)
#pragma unroll
      for (int fn = 0; fn < 4; ++fn) {
        int c = col0 + fn * 16;
#pragma unroll
        for (int i = 0; i < 4; ++i)
          C[(size_t)(row0 + fm * 16 + i) * ldc + c] = f2bf(acc[fm][fn][i]);
      }
  } else if constexpr (MODE == GM_FC1) {
    short* C = (short*)Cg;
#pragma unroll
    for (int fm = 0; fm < 4; ++fm)
#pragma unroll
      for (int fn = 0; fn < 4; ++fn) {
        int c = col0 + fn * 16;
        float bv = bias[c];
#pragma unroll
        for (int i = 0; i < 4; ++i)
          C[(size_t)(row0 + fm * 16 + i) * ldc + c] = f2bf(fmaxf(acc[fm][fn][i] + bv, 0.f));
      }
  } else if constexpr (MODE == GM_RESID) {
    float* C = (float*)Cg;
#pragma unroll
    for (int fm = 0; fm < 4; ++fm)
#pragma unroll
      for (int fn = 0; fn < 4; ++fn) {
        int c = col0 + fn * 16;
        float bv = bias[c];
#pragma unroll
        for (int i = 0; i < 4; ++i) {
          size_t o = (size_t)(row0 + fm * 16 + i) * ldc + c;
          C[o] = resid[o] + acc[fm][fn][i] + bv;
        }
      }
  } else if constexpr (MODE == GM_HEAD) {
    __shared__ float redm[2][2][64];
    __shared__ float reds[2][2][64];
    float* C = (float*)Cg;
    bool okv[4]; float bv[4];
#pragma unroll
    for (int fn = 0; fn < 4; ++fn) {
      int c = col0 + fn * 16;
      okv[fn] = c < VOC;
      bv[fn] = okv[fn] ? bias[c] : 0.f;
    }
#pragma unroll
    for (int fm = 0; fm < 4; ++fm)
#pragma unroll
      for (int fn = 0; fn < 4; ++fn)
#pragma unroll
        for (int i = 0; i < 4; ++i) acc[fm][fn][i] += bv[fn];
    // per-row LSE partial (max then sum; 16 lanes per row)
#pragma unroll
    for (int fm = 0; fm < 4; ++fm)
#pragma unroll
      for (int i = 0; i < 4; ++i) {
        float v0 = okv[0] ? acc[fm][0][i] : -1e30f;
        float v1 = okv[1] ? acc[fm][1][i] : -1e30f;
        float v2 = okv[2] ? acc[fm][2][i] : -1e30f;
        float v3 = okv[3] ? acc[fm][3][i] : -1e30f;
        float mx = fmaxf(fmaxf(v0, v1), fmaxf(v2, v3));
#pragma unroll
        for (int o = 8; o; o >>= 1) mx = fmaxf(mx, __shfl_xor(mx, o, 64));
        float sm = __expf(v0 - mx) + __expf(v1 - mx) + __expf(v2 - mx) + __expf(v3 - mx);
#pragma unroll
        for (int o = 8; o; o >>= 1) sm += __shfl_xor(sm, o, 64);
        if (lr == 0) {
          int rl = fm * 16 + (kq << 2) + i;
          redm[wm][wn][rl] = mx; reds[wm][wn][rl] = sm;
        }
      }
    __syncthreads();
    if (tid < 128) {
      int wmm = tid >> 6, rl = tid & 63;
      float m0 = redm[wmm][0][rl], m1 = redm[wmm][1][rl];
      float s0 = reds[wmm][0][rl], s1 = reds[wmm][1][rl];
      float M = fmaxf(m0, m1);
      float S = s0 * __expf(m0 - M) + s1 * __expf(m1 - M);
      int r = bm * 128 + wmm * 64 + rl;
      pm[(size_t)r * NCH + bn] = M;
      ps[(size_t)r * NCH + bn] = S;
    }
    // C store: stage 32-row chunks in LDS (aliased onto dead sA/sB dbuf);
    // lane-consecutive dword nt stores (full-line coverage, no amplification)
    float (*cst)[132] = reinterpret_cast<float(*)[132]>(smem);  // 32*132*4 = 16896 B <= 32768 B
    int colbase = bn * 128;
#pragma unroll
    for (int c = 0; c < 4; ++c) {
      __syncthreads();
      if (wm == (c >> 1)) {
        int fmb = (c & 1) * 2;
#pragma unroll
        for (int f2 = 0; f2 < 2; ++f2)
#pragma unroll
          for (int fn = 0; fn < 4; ++fn)
#pragma unroll
            for (int i = 0; i < 4; ++i)
              cst[f2 * 16 + kq * 4 + i][wn * 64 + fn * 16 + lr] = acc[fmb + f2][fn][i];
      }
      __syncthreads();
      int rowg = bm * 128 + c * 32;
#pragma unroll
      for (int pp = 0; pp < 16; ++pp) {
        int idx = pp * 256 + tid;
        int rw = idx >> 7, cc = idx & 127;
        int gc = colbase + cc;
        if (gc < VOC)
          __builtin_nontemporal_store(cst[rw][cc], &C[(size_t)(rowg + rw) * VOC + gc]);
      }
    }
  }
}

// ---------------- combine per-chunk LSE partials -> per-row loss ----------------
__global__ __launch_bounds__(256) void lsecomb_k(const float* __restrict__ pm, const float* __restrict__ ps,
                                                 const float* __restrict__ logits, const int* __restrict__ tgt,
                                                 float* __restrict__ rowloss) {
  int wave = threadIdx.x >> 6, lane = threadIdx.x & 63;
  int r = (blockIdx.x << 2) + wave;
  float m = -1e30f, s = 0.f;
  for (int i = lane; i < NCH; i += 64) {
    float bm = pm[(size_t)r * NCH + i], bs = ps[(size_t)r * NCH + i];
    float M = fmaxf(m, bm);
    s = s * __expf(m - M) + bs * __expf(bm - M);
    m = M;
  }
#pragma unroll
  for (int o = 32; o; o >>= 1) {
    float mo = __shfl_xor(m, o, 64), so = __shfl_xor(s, o, 64);
    float M = fmaxf(m, mo);
    s = s * __expf(m - M) + so * __expf(mo - M);
    m = M;
  }
  if (lane == 0) rowloss[r] = m + __logf(s) - logits[(size_t)r * VOC + tgt[r]];
}

__global__ __launch_bounds__(256) void loss_final_k(const float* __restrict__ rowloss,
                                                    float* __restrict__ out) {
  __shared__ float sb[256];
  int tid = threadIdx.x;
  float s = 0.f;
  for (int i = tid; i < NTOK; i += 256) s += rowloss[i];
  sb[tid] = s;
  __syncthreads();
  for (int o = 128; o; o >>= 1) {
    if (tid < o) sb[tid] += sb[tid + o];
    __syncthreads();
  }
  if (tid == 0) out[0] = sb[0] * (1.f / NTOK);
}

extern "C" void kernel_launch(void* const* d_in, const int* in_sizes, int n_in,
                              void* d_out, int out_size, void* d_ws, size_t ws_size,
                              hipStream_t stream) {
  const int* idx = (const int*)d_in[0];
  const int* tgt = (const int*)d_in[1];
  const float* tok = (const float*)d_in[2];
  const float* pos = (const float*)d_in[3];
  const float* Wq = (const float*)d_in[4];
  const float* Wk = (const float*)d_in[5];
  const float* Wv = (const float*)d_in[6];
  const float* Wp = (const float*)d_in[7];
  const float* bp = (const float*)d_in[8];
  const float* W1 = (const float*)d_in[9];
  const float* b1 = (const float*)d_in[10];
  const float* W2 = (const float*)d_in[11];
  const float* b2 = (const float*)d_in[12];
  const float* ln1g = (const float*)d_in[13];
  const float* ln1b = (const float*)d_in[14];
  const float* ln2g = (const float*)d_in[15];
  const float* ln2b = (const float*)d_in[16];
  const float* lnfg = (const float*)d_in[17];
  const float* lnfb = (const float*)d_in[18];
  const float* Wh = (const float*)d_in[19];
  const float* bh = (const float*)d_in[20];

  char* wp = (char*)d_ws;
  auto take = [&](size_t elems, size_t esz) {
    void* r = (void*)wp;
    wp += (elems * esz + 255) & ~(size_t)255;
    return r;
  };
  short* wqkv_t = (short*)take((size_t)NL * QKVW * EMB, 2);
  short* wproj_t = (short*)take((size_t)NL * EMB * EMB, 2);
  short* w1_t = (short*)take((size_t)NL * FF * EMB, 2);
  short* w2_t = (short*)take((size_t)NL * EMB * FF, 2);
  short* whead_t = (short*)take((size_t)VOCP * EMB, 2);
  float* x = (float*)take((size_t)NTOK * EMB, 4);
  short* hb = (short*)take((size_t)NTOK * EMB, 2);
  short* qkv = (short*)take((size_t)NTOK * QKVW, 2);
  float* sc = (float*)take((size_t)96 * TT * TT, 4);
  short* vt = (short*)take((size_t)96 * 64 * TT, 2);
  short* att = (short*)take((size_t)NTOK * EMB, 2);
  short* f1 = (short*)take((size_t)NTOK * FF, 2);
  float* rl = (float*)take((size_t)NTOK, 4);

  float* pm = sc;
  float* ps = sc + (size_t)NTOK * NCH;

  tcast_k<<<dim3(12, 12, NL), 256, 0, stream>>>(Wq, wqkv_t, EMB, EMB, (long)EMB * EMB, (long)QKVW * EMB);
  tcast_k<<<dim3(12, 12, NL), 256, 0, stream>>>(Wk, wqkv_t + EMB * EMB, EMB, EMB, (long)EMB * EMB, (long)QKVW * EMB);
  tcast_k<<<dim3(12, 12, NL), 256, 0, stream>>>(Wv, wqkv_t + 2 * EMB * EMB, EMB, EMB, (long)EMB * EMB, (long)QKVW * EMB);
  tcast_k<<<dim3(12, 12, NL), 256, 0, stream>>>(Wp, wproj_t, EMB, EMB, (long)EMB * EMB, (long)EMB * EMB);
  tcast_k<<<dim3(48, 12, NL), 256, 0, stream>>>(W1, w1_t, EMB, FF, (long)EMB * FF, (long)FF * EMB);
  tcast_k<<<dim3(12, 48, NL), 256, 0, stream>>>(W2, w2_t, FF, EMB, (long)FF * EMB, (long)EMB * FF);
  tcast_k<<<dim3(VOCP / 32, 12, 1), 256, 0, stream>>>(Wh, whead_t, EMB, VOC, 0, 0);

  embed_k<<<NTOK, EMB, 0, stream>>>(idx, tok, pos, x);

  for (int l = 0; l < NL; ++l) {
    ln_k<<<NTOK / 4, 256, 0, stream>>>(x, ln1g + l * EMB, ln1b + l * EMB, hb);
    gemm_k<GM_QKV><<<dim3(32, 9), 256, 0, stream>>>(hb, wqkv_t + (size_t)l * QKVW * EMB, qkv,
        nullptr, nullptr, EMB, EMB, EMB, QKVW, 0.f, nullptr, nullptr);
    vtrans_k<<<dim3(4, 96), 256, 0, stream>>>(qkv, vt);
    attn_k<<<dim3(4, 96), 256, 0, stream>>>(qkv, vt, att);
    gemm_k<GM_RESID><<<dim3(32, 3), 256, 0, stream>>>(att, wproj_t + (size_t)l * EMB * EMB, x,
        bp + l * EMB, x, EMB, EMB, EMB, EMB, 0.f, nullptr, nullptr);
    ln_k<<<NTOK / 4, 256, 0, stream>>>(x, ln2g + l * EMB, ln2b + l * EMB, hb);
    gemm_k<GM_FC1><<<dim3(32, 12), 256, 0, stream>>>(hb, w1_t + (size_t)l * FF * EMB, f1,
        b1 + l * FF, nullptr, EMB, EMB, EMB, FF, 0.f, nullptr, nullptr);
    gemm_k<GM_RESID><<<dim3(32, 3), 256, 0, stream>>>(f1, w2_t + (size_t)l * EMB * FF, x,
        b2 + l * EMB, x, FF, FF, FF, EMB, 0.f, nullptr, nullptr);
  }

  ln_k<<<NTOK / 4, 256, 0, stream>>>(x, lnfg, lnfb, hb);
  gemm_k<GM_HEAD><<<dim3(32, NCH), 256, 0, stream>>>(hb, whead_t, (float*)d_out,
      bh, nullptr, EMB, EMB, EMB, VOC, 0.f, pm, ps);
  lsecomb_k<<<NTOK / 4, 256, 0, stream>>>(pm, ps, (const float*)d_out, tgt, rl);
  loss_final_k<<<1, 256, 0, stream>>>(rl, (float*)d_out + (size_t)NTOK * VOC);
}

// Round 12
// 969.433 us; speedup vs baseline: 1.7162x; 1.2076x over previous
//
#include <hip/hip_runtime.h>

#define NL 6
#define EMB 384
#define NH 6
#define HSZ 64
#define TT 256
#define NTOK 4096
#define VOC 50257
#define VOCP 50304
#define FF 1536
#define QKVW 1152
#define NCH 393

typedef __attribute__((ext_vector_type(8))) short bf16x8;
typedef __attribute__((ext_vector_type(4))) float f32x4;

__device__ __forceinline__ short f2bf(float f) {
  unsigned u = __float_as_uint(f);
  u = (u + 0x7fffu + ((u >> 16) & 1u)) >> 16;
  return (short)u;
}

// involutive 16B-granular LDS swizzle: bits[5:4] ^= f(bits[8:6]); swz(swz(x)) == x
__device__ __forceinline__ int swz16(int b) {
  return b ^ (((((b >> 6) ^ (b >> 8)) & 1) << 4) | (((b >> 7) & 1) << 5));
}

__device__ __forceinline__ void gl16(const void* g, void* l) {
  __builtin_amdgcn_global_load_lds(
      (const __attribute__((address_space(1))) unsigned*)g,
      (__attribute__((address_space(3))) unsigned*)l, 16, 0, 0);
}

// ---------------- embedding ----------------
__global__ void embed_k(const int* __restrict__ idx, const float* __restrict__ tok,
                        const float* __restrict__ pos, float* __restrict__ x) {
  int row = blockIdx.x, col = threadIdx.x;
  int t = idx[row];
  x[(size_t)row * EMB + col] = tok[(size_t)t * EMB + col] + pos[(size_t)(row & 255) * EMB + col];
}

// ---------------- transpose + cast f32 -> bf16 : dst[n][k] = src[k][n] ----------------
__global__ __launch_bounds__(256) void tcast_k(const float* __restrict__ src, short* __restrict__ dst,
                                               int K, int N, long sstr, long dstr) {
  src += (size_t)blockIdx.z * sstr;
  dst += (size_t)blockIdx.z * dstr;
  __shared__ float tile[32][33];
  int lx = threadIdx.x & 31, ly = threadIdx.x >> 5;
  int k0 = blockIdx.y << 5, n0 = blockIdx.x << 5;
#pragma unroll
  for (int j = 0; j < 4; ++j) {
    int k = k0 + ly + (j << 3), n = n0 + lx;
    tile[ly + (j << 3)][lx] = (n < N) ? src[(size_t)k * N + n] : 0.f;
  }
  __syncthreads();
#pragma unroll
  for (int j = 0; j < 4; ++j) {
    int n = n0 + ly + (j << 3), k = k0 + lx;
    dst[(size_t)n * K + k] = f2bf(tile[lx][ly + (j << 3)]);
  }
}

// ---------------- layernorm (f32 in) -> bf16 out ----------------
__global__ __launch_bounds__(256) void ln_k(const float* __restrict__ x, const float* __restrict__ g,
                                            const float* __restrict__ b, short* __restrict__ out) {
  int wave = threadIdx.x >> 6, lane = threadIdx.x & 63;
  int row = (blockIdx.x << 2) + wave;
  const float* p = x + (size_t)row * EMB;
  float v[6]; float s = 0.f;
#pragma unroll
  for (int j = 0; j < 6; ++j) { v[j] = p[lane + (j << 6)]; s += v[j]; }
#pragma unroll
  for (int o = 32; o; o >>= 1) s += __shfl_xor(s, o, 64);
  float mu = s * (1.f / EMB);
  float q = 0.f;
#pragma unroll
  for (int j = 0; j < 6; ++j) { float d = v[j] - mu; q += d * d; }
#pragma unroll
  for (int o = 32; o; o >>= 1) q += __shfl_xor(q, o, 64);
  float rstd = rsqrtf(q * (1.f / EMB) + 1e-5f);
  short* op = out + (size_t)row * EMB;
#pragma unroll
  for (int j = 0; j < 6; ++j) {
    int c = lane + (j << 6);
    op[c] = f2bf((v[j] - mu) * rstd * g[c] + b[c]);
  }
}

// ---------------- V transpose: qkv -> vt[bh][d][t], d<64 ----------------
__global__ __launch_bounds__(256) void vtrans_k(const short* __restrict__ qkv, short* __restrict__ vt) {
  int bh = blockIdx.y; int b = bh / NH, h = bh % NH;
  int t0 = blockIdx.x << 6;
  __shared__ short tile[64][72];
  int tid = threadIdx.x;
#pragma unroll
  for (int pass = 0; pass < 2; ++pass) {
    int tl = pass * 32 + (tid >> 3);
    int d0 = (tid & 7) << 3;
    uint4 v = *(const uint4*)&qkv[((size_t)(b * TT + t0 + tl)) * QKVW + 2 * EMB + h * HSZ + d0];
    *(uint4*)&tile[tl][d0] = v;
  }
  __syncthreads();
  int d = tid >> 2, tc = (tid & 3) << 4;
  short* dst = &vt[((size_t)bh * 64 + d) * TT + t0 + tc];
#pragma unroll
  for (int j = 0; j < 16; ++j) dst[j] = tile[tc + j][d];
}

// ---------------- fused attention: scores + causal softmax + PV (causal-trimmed) ------------
template <int KFB>
__device__ __forceinline__ void attn_body(const short* __restrict__ qkv,
                                          const short* __restrict__ vt,
                                          short* __restrict__ att,
                                          short (*P)[260], int qt, int bh, int tid) {
  const float SCALE = 0.051031036307982884f;  // 1/sqrt(384)
  int b = bh / NH, h = bh % NH;
  int w = tid >> 6, lane = tid & 63;
  int lr = lane & 15, g = lane >> 4;
  int qbase = qt * 64 + w * 16;

  const short* qrow = qkv + (size_t)(b * TT + qbase + lr) * QKVW + h * HSZ;
  bf16x8 qa0 = *(const bf16x8*)(qrow + g * 8);
  bf16x8 qa1 = *(const bf16x8*)(qrow + 32 + g * 8);

  f32x4 zero = {0.f, 0.f, 0.f, 0.f};
  f32x4 s[KFB];
#pragma unroll
  for (int kf = 0; kf < KFB; ++kf) s[kf] = zero;
#pragma unroll
  for (int kf = 0; kf < KFB; ++kf) {
    const short* krow = qkv + (size_t)(b * TT + kf * 16 + lr) * QKVW + EMB + h * HSZ;
    bf16x8 kb0 = *(const bf16x8*)(krow + g * 8);
    bf16x8 kb1 = *(const bf16x8*)(krow + 32 + g * 8);
    s[kf] = __builtin_amdgcn_mfma_f32_16x16x32_bf16(qa0, kb0, s[kf], 0, 0, 0);
    s[kf] = __builtin_amdgcn_mfma_f32_16x16x32_bf16(qa1, kb1, s[kf], 0, 0, 0);
  }

#pragma unroll
  for (int i = 0; i < 4; ++i) {
    int qg = qbase + g * 4 + i;
    float m = -1e30f;
#pragma unroll
    for (int kf = 0; kf < KFB; ++kf) {
      float v = s[kf][i] * SCALE;
      if (kf * 16 + lr > qg) v = -1e30f;
      s[kf][i] = v;
      m = fmaxf(m, v);
    }
#pragma unroll
    for (int o = 8; o; o >>= 1) m = fmaxf(m, __shfl_xor(m, o, 64));
    float sum = 0.f;
#pragma unroll
    for (int kf = 0; kf < KFB; ++kf) {
      float e = __expf(s[kf][i] - m);
      s[kf][i] = e;
      sum += e;
    }
#pragma unroll
    for (int o = 8; o; o >>= 1) sum += __shfl_xor(sum, o, 64);
    float inv = 1.f / sum;
#pragma unroll
    for (int kf = 0; kf < KFB; ++kf)
      P[w * 16 + g * 4 + i][kf * 16 + lr] = f2bf(s[kf][i] * inv);
  }

  f32x4 o4[4];
#pragma unroll
  for (int nf = 0; nf < 4; ++nf) o4[nf] = zero;
  const short* vbase = vt + (size_t)bh * 64 * TT;
#pragma unroll
  for (int ks = 0; ks < KFB / 2; ++ks) {
    bf16x8 pa = *(const bf16x8*)&P[w * 16 + lr][ks * 32 + g * 8];
#pragma unroll
    for (int nf = 0; nf < 4; ++nf) {
      bf16x8 vb = *(const bf16x8*)(vbase + (size_t)(nf * 16 + lr) * TT + ks * 32 + g * 8);
      o4[nf] = __builtin_amdgcn_mfma_f32_16x16x32_bf16(pa, vb, o4[nf], 0, 0, 0);
    }
  }
#pragma unroll
  for (int nf = 0; nf < 4; ++nf)
#pragma unroll
    for (int i = 0; i < 4; ++i)
      att[(size_t)(b * TT + qbase + g * 4 + i) * EMB + h * HSZ + nf * 16 + lr] = f2bf(o4[nf][i]);
}

__global__ __launch_bounds__(256) void attn_k(const short* __restrict__ qkv,
                                              const short* __restrict__ vt,
                                              short* __restrict__ att) {
  __shared__ short P[64][260];
  int qt = blockIdx.x, bh = blockIdx.y, tid = threadIdx.x;
  if (qt == 0)      attn_body<4>(qkv, vt, att, P, 0, bh, tid);
  else if (qt == 1) attn_body<8>(qkv, vt, att, P, 1, bh, tid);
  else if (qt == 2) attn_body<12>(qkv, vt, att, P, 2, bh, tid);
  else              attn_body<16>(qkv, vt, att, P, 3, bh, tid);
}

// ---------------- generic 128x128 MFMA GEMM: C = A[M,K] * Bt[N,K]^T ----------------
#define GM_QKV 0
#define GM_FC1 4
#define GM_HEAD 5

template <int MODE>
__global__ __launch_bounds__(256) void gemm_k(
    const short* __restrict__ Ag, const short* __restrict__ Btg, void* Cg,
    const float* __restrict__ bias, const float* resid,
    int K, int lda, int ldb, int ldc, float scale,
    float* __restrict__ pm, float* __restrict__ ps) {
  __shared__ alignas(1024) char smem[2 * 2 * 128 * 32 * 2];  // sA dbuf + sB dbuf (32 KB)
  short* sA = (short*)smem;
  short* sB = (short*)(smem + 16384);
  int tid = threadIdx.x;
  int bm = blockIdx.x, bn = blockIdx.y;
  int wave = tid >> 6, lane = tid & 63;
  int wm = wave >> 1, wn = wave & 1;
  int lr = lane & 15, kq = lane >> 4;
  size_t lda2 = (size_t)lda * 2, ldb2 = (size_t)ldb * 2;

  int p = wave * 1024 + lane * 16;
  int q = swz16(p);
  int srow = q >> 6, scb = q & 63;
  const char* gA = (const char*)Ag + (size_t)(bm * 128 + srow) * lda2 + scb;
  const char* gB = (const char*)Btg + (size_t)(bn * 128 + srow) * ldb2 + scb;
  char* lA0 = (char*)sA + wave * 1024; char* lA1 = lA0 + 4096;
  char* lB0 = (char*)sB + wave * 1024; char* lB1 = lB0 + 4096;

  const char* apf[4]; const char* bpf[4];
#pragma unroll
  for (int f = 0; f < 4; ++f) {
    int La = (wm * 64 + f * 16 + lr) * 64 + kq * 16;
    apf[f] = (const char*)sA + swz16(La);
    int Lb = (wn * 64 + f * 16 + lr) * 64 + kq * 16;
    bpf[f] = (const char*)sB + swz16(Lb);
  }

  f32x4 zero = {0.f, 0.f, 0.f, 0.f};
  f32x4 acc[4][4];
#pragma unroll
  for (int i = 0; i < 4; ++i)
#pragma unroll
    for (int j = 0; j < 4; ++j) acc[i][j] = zero;

  // prologue: stage k-step 0 into buf0
  gl16(gA, lA0); gl16(gA + 64 * lda2, lA1);
  gl16(gB, lB0); gl16(gB + 64 * ldb2, lB1);
  __syncthreads();

  int nt = K >> 5;
  for (int t = 0; t < nt; ++t) {
    int cur = (t & 1) << 13, nxt = (~t & 1) << 13;
    if (t + 1 < nt) {
      const char* ga2 = gA + (size_t)(t + 1) * 64;
      const char* gb2 = gB + (size_t)(t + 1) * 64;
      gl16(ga2, lA0 + nxt); gl16(ga2 + 64 * lda2, lA1 + nxt);
      gl16(gb2, lB0 + nxt); gl16(gb2 + 64 * ldb2, lB1 + nxt);
    }
    bf16x8 af[4], bfr[4];
#pragma unroll
    for (int f = 0; f < 4; ++f) {
      af[f] = *(const bf16x8*)(apf[f] + cur);
      bfr[f] = *(const bf16x8*)(bpf[f] + cur);
    }
#pragma unroll
    for (int i = 0; i < 4; ++i)
#pragma unroll
      for (int j = 0; j < 4; ++j)
        acc[i][j] = __builtin_amdgcn_mfma_f32_16x16x32_bf16(af[i], bfr[j], acc[i][j], 0, 0, 0);
    __syncthreads();
  }

  int row0 = bm * 128 + wm * 64 + (kq << 2);
  int col0 = bn * 128 + wn * 64 + lr;

  if constexpr (MODE == GM_QKV) {
    short* C = (short*)Cg;
#pragma unroll
    for (int fm = 0; fm < 4; ++fm)
#pragma unroll
      for (int fn = 0; fn < 4; ++fn) {
        int c = col0 + fn * 16;
#pragma unroll
        for (int i = 0; i < 4; ++i)
          C[(size_t)(row0 + fm * 16 + i) * ldc + c] = f2bf(acc[fm][fn][i]);
      }
  } else if constexpr (MODE == GM_FC1) {
    short* C = (short*)Cg;
#pragma unroll
    for (int fm = 0; fm < 4; ++fm)
#pragma unroll
      for (int fn = 0; fn < 4; ++fn) {
        int c = col0 + fn * 16;
        float bv = bias[c];
#pragma unroll
        for (int i = 0; i < 4; ++i)
          C[(size_t)(row0 + fm * 16 + i) * ldc + c] = f2bf(fmaxf(acc[fm][fn][i] + bv, 0.f));
      }
  } else if constexpr (MODE == GM_HEAD) {
    __shared__ float redm[2][2][64];
    __shared__ float reds[2][2][64];
    float* C = (float*)Cg;
    bool okv[4]; float bv[4];
#pragma unroll
    for (int fn = 0; fn < 4; ++fn) {
      int c = col0 + fn * 16;
      okv[fn] = c < VOC;
      bv[fn] = okv[fn] ? bias[c] : 0.f;
    }
#pragma unroll
    for (int fm = 0; fm < 4; ++fm)
#pragma unroll
      for (int fn = 0; fn < 4; ++fn)
#pragma unroll
        for (int i = 0; i < 4; ++i) acc[fm][fn][i] += bv[fn];
    // per-row LSE partial (max then sum; 16 lanes per row)
#pragma unroll
    for (int fm = 0; fm < 4; ++fm)
#pragma unroll
      for (int i = 0; i < 4; ++i) {
        float v0 = okv[0] ? acc[fm][0][i] : -1e30f;
        float v1 = okv[1] ? acc[fm][1][i] : -1e30f;
        float v2 = okv[2] ? acc[fm][2][i] : -1e30f;
        float v3 = okv[3] ? acc[fm][3][i] : -1e30f;
        float mx = fmaxf(fmaxf(v0, v1), fmaxf(v2, v3));
#pragma unroll
        for (int o = 8; o; o >>= 1) mx = fmaxf(mx, __shfl_xor(mx, o, 64));
        float sm = __expf(v0 - mx) + __expf(v1 - mx) + __expf(v2 - mx) + __expf(v3 - mx);
#pragma unroll
        for (int o = 8; o; o >>= 1) sm += __shfl_xor(sm, o, 64);
        if (lr == 0) {
          int rl = fm * 16 + (kq << 2) + i;
          redm[wm][wn][rl] = mx; reds[wm][wn][rl] = sm;
        }
      }
    __syncthreads();
    if (tid < 128) {
      int wmm = tid >> 6, rl = tid & 63;
      float m0 = redm[wmm][0][rl], m1 = redm[wmm][1][rl];
      float s0 = reds[wmm][0][rl], s1 = reds[wmm][1][rl];
      float M = fmaxf(m0, m1);
      float S = s0 * __expf(m0 - M) + s1 * __expf(m1 - M);
      int r = bm * 128 + wmm * 64 + rl;
      pm[(size_t)r * NCH + bn] = M;
      ps[(size_t)r * NCH + bn] = S;
    }
    // C store: stage 32-row chunks in LDS (aliased onto dead sA/sB dbuf);
    // lane-consecutive dword nt stores (full-line coverage, no amplification)
    float (*cst)[132] = reinterpret_cast<float(*)[132]>(smem);
    int colbase = bn * 128;
#pragma unroll
    for (int c = 0; c < 4; ++c) {
      __syncthreads();
      if (wm == (c >> 1)) {
        int fmb = (c & 1) * 2;
#pragma unroll
        for (int f2 = 0; f2 < 2; ++f2)
#pragma unroll
          for (int fn = 0; fn < 4; ++fn)
#pragma unroll
            for (int i = 0; i < 4; ++i)
              cst[f2 * 16 + kq * 4 + i][wn * 64 + fn * 16 + lr] = acc[fmb + f2][fn][i];
      }
      __syncthreads();
      int rowg = bm * 128 + c * 32;
#pragma unroll
      for (int pp = 0; pp < 16; ++pp) {
        int idx = pp * 256 + tid;
        int rw = idx >> 7, cc = idx & 127;
        int gc = colbase + cc;
        if (gc < VOC)
          __builtin_nontemporal_store(cst[rw][cc], &C[(size_t)(rowg + rw) * VOC + gc]);
      }
    }
  }
}

// ---------------- 64x64-tile residual GEMM: C = resid + A[M,K]*Bt[N,K]^T + bias ------------
// grid (M/64, N/64); 4 waves of 32x32; full-chip utilization for small-N GEMMs.
__global__ __launch_bounds__(256) void gemm64_k(
    const short* __restrict__ Ag, const short* __restrict__ Btg, float* __restrict__ C,
    const float* __restrict__ bias, const float* __restrict__ resid,
    int K, int lda, int ldb, int ldc) {
  __shared__ alignas(1024) short sA[2 * 64 * 32];  // 8 KB
  __shared__ alignas(1024) short sB[2 * 64 * 32];  // 8 KB
  int tid = threadIdx.x;
  int bm = blockIdx.x, bn = blockIdx.y;
  int wave = tid >> 6, lane = tid & 63;
  int wm = wave >> 1, wn = wave & 1;
  int lr = lane & 15, kq = lane >> 4;
  size_t lda2 = (size_t)lda * 2, ldb2 = (size_t)ldb * 2;

  int p = wave * 1024 + lane * 16;   // 4 waves cover the 4 KB tile
  int q = swz16(p);
  int srow = q >> 6, scb = q & 63;
  const char* gA = (const char*)Ag + (size_t)(bm * 64 + srow) * lda2 + scb;
  const char* gB = (const char*)Btg + (size_t)(bn * 64 + srow) * ldb2 + scb;
  char* lA0 = (char*)sA + wave * 1024;
  char* lB0 = (char*)sB + wave * 1024;

  const char* apf[2]; const char* bpf[2];
#pragma unroll
  for (int f = 0; f < 2; ++f) {
    apf[f] = (const char*)sA + swz16((wm * 32 + f * 16 + lr) * 64 + kq * 16);
    bpf[f] = (const char*)sB + swz16((wn * 32 + f * 16 + lr) * 64 + kq * 16);
  }

  f32x4 zero = {0.f, 0.f, 0.f, 0.f};
  f32x4 acc[2][2];
#pragma unroll
  for (int i = 0; i < 2; ++i)
#pragma unroll
    for (int j = 0; j < 2; ++j) acc[i][j] = zero;

  // prologue: stage k-step 0 into buf0
  gl16(gA, lA0);
  gl16(gB, lB0);
  __syncthreads();

  int nt = K >> 5;
  for (int t = 0; t < nt; ++t) {
    int cur = (t & 1) << 12, nxt = (~t & 1) << 12;
    if (t + 1 < nt) {
      gl16(gA + (size_t)(t + 1) * 64, lA0 + nxt);
      gl16(gB + (size_t)(t + 1) * 64, lB0 + nxt);
    }
    bf16x8 af[2], bfr[2];
#pragma unroll
    for (int f = 0; f < 2; ++f) {
      af[f] = *(const bf16x8*)(apf[f] + cur);
      bfr[f] = *(const bf16x8*)(bpf[f] + cur);
    }
#pragma unroll
    for (int i = 0; i < 2; ++i)
#pragma unroll
      for (int j = 0; j < 2; ++j)
        acc[i][j] = __builtin_amdgcn_mfma_f32_16x16x32_bf16(af[i], bfr[j], acc[i][j], 0, 0, 0);
    __syncthreads();
  }

  int row0 = bm * 64 + wm * 32 + (kq << 2);
  int col0 = bn * 64 + wn * 32 + lr;
#pragma unroll
  for (int fm = 0; fm < 2; ++fm)
#pragma unroll
    for (int fn = 0; fn < 2; ++fn) {
      int c = col0 + fn * 16;
      float bv = bias[c];
#pragma unroll
      for (int i = 0; i < 4; ++i) {
        size_t o = (size_t)(row0 + fm * 16 + i) * ldc + c;
        C[o] = resid[o] + acc[fm][fn][i] + bv;
      }
    }
}

// ---------------- combine per-chunk LSE partials -> per-row loss ----------------
__global__ __launch_bounds__(256) void lsecomb_k(const float* __restrict__ pm, const float* __restrict__ ps,
                                                 const float* __restrict__ logits, const int* __restrict__ tgt,
                                                 float* __restrict__ rowloss) {
  int wave = threadIdx.x >> 6, lane = threadIdx.x & 63;
  int r = (blockIdx.x << 2) + wave;
  float m = -1e30f, s = 0.f;
  for (int i = lane; i < NCH; i += 64) {
    float bm = pm[(size_t)r * NCH + i], bs = ps[(size_t)r * NCH + i];
    float M = fmaxf(m, bm);
    s = s * __expf(m - M) + bs * __expf(bm - M);
    m = M;
  }
#pragma unroll
  for (int o = 32; o; o >>= 1) {
    float mo = __shfl_xor(m, o, 64), so = __shfl_xor(s, o, 64);
    float M = fmaxf(m, mo);
    s = s * __expf(m - M) + so * __expf(mo - M);
    m = M;
  }
  if (lane == 0) rowloss[r] = m + __logf(s) - logits[(size_t)r * VOC + tgt[r]];
}

__global__ __launch_bounds__(256) void loss_final_k(const float* __restrict__ rowloss,
                                                    float* __restrict__ out) {
  __shared__ float sb[256];
  int tid = threadIdx.x;
  float s = 0.f;
  for (int i = tid; i < NTOK; i += 256) s += rowloss[i];
  sb[tid] = s;
  __syncthreads();
  for (int o = 128; o; o >>= 1) {
    if (tid < o) sb[tid] += sb[tid + o];
    __syncthreads();
  }
  if (tid == 0) out[0] = sb[0] * (1.f / NTOK);
}

extern "C" void kernel_launch(void* const* d_in, const int* in_sizes, int n_in,
                              void* d_out, int out_size, void* d_ws, size_t ws_size,
                              hipStream_t stream) {
  const int* idx = (const int*)d_in[0];
  const int* tgt = (const int*)d_in[1];
  const float* tok = (const float*)d_in[2];
  const float* pos = (const float*)d_in[3];
  const float* Wq = (const float*)d_in[4];
  const float* Wk = (const float*)d_in[5];
  const float* Wv = (const float*)d_in[6];
  const float* Wp = (const float*)d_in[7];
  const float* bp = (const float*)d_in[8];
  const float* W1 = (const float*)d_in[9];
  const float* b1 = (const float*)d_in[10];
  const float* W2 = (const float*)d_in[11];
  const float* b2 = (const float*)d_in[12];
  const float* ln1g = (const float*)d_in[13];
  const float* ln1b = (const float*)d_in[14];
  const float* ln2g = (const float*)d_in[15];
  const float* ln2b = (const float*)d_in[16];
  const float* lnfg = (const float*)d_in[17];
  const float* lnfb = (const float*)d_in[18];
  const float* Wh = (const float*)d_in[19];
  const float* bh = (const float*)d_in[20];

  char* wp = (char*)d_ws;
  auto take = [&](size_t elems, size_t esz) {
    void* r = (void*)wp;
    wp += (elems * esz + 255) & ~(size_t)255;
    return r;
  };
  short* wqkv_t = (short*)take((size_t)NL * QKVW * EMB, 2);
  short* wproj_t = (short*)take((size_t)NL * EMB * EMB, 2);
  short* w1_t = (short*)take((size_t)NL * FF * EMB, 2);
  short* w2_t = (short*)take((size_t)NL * EMB * FF, 2);
  short* whead_t = (short*)take((size_t)VOCP * EMB, 2);
  float* x = (float*)take((size_t)NTOK * EMB, 4);
  short* hb = (short*)take((size_t)NTOK * EMB, 2);
  short* qkv = (short*)take((size_t)NTOK * QKVW, 2);
  float* sc = (float*)take((size_t)96 * TT * TT, 4);
  short* vt = (short*)take((size_t)96 * 64 * TT, 2);
  short* att = (short*)take((size_t)NTOK * EMB, 2);
  short* f1 = (short*)take((size_t)NTOK * FF, 2);
  float* rl = (float*)take((size_t)NTOK, 4);

  float* pm = sc;
  float* ps = sc + (size_t)NTOK * NCH;

  tcast_k<<<dim3(12, 12, NL), 256, 0, stream>>>(Wq, wqkv_t, EMB, EMB, (long)EMB * EMB, (long)QKVW * EMB);
  tcast_k<<<dim3(12, 12, NL), 256, 0, stream>>>(Wk, wqkv_t + EMB * EMB, EMB, EMB, (long)EMB * EMB, (long)QKVW * EMB);
  tcast_k<<<dim3(12, 12, NL), 256, 0, stream>>>(Wv, wqkv_t + 2 * EMB * EMB, EMB, EMB, (long)EMB * EMB, (long)QKVW * EMB);
  tcast_k<<<dim3(12, 12, NL), 256, 0, stream>>>(Wp, wproj_t, EMB, EMB, (long)EMB * EMB, (long)EMB * EMB);
  tcast_k<<<dim3(48, 12, NL), 256, 0, stream>>>(W1, w1_t, EMB, FF, (long)EMB * FF, (long)FF * EMB);
  tcast_k<<<dim3(12, 48, NL), 256, 0, stream>>>(W2, w2_t, FF, EMB, (long)FF * EMB, (long)EMB * FF);
  tcast_k<<<dim3(VOCP / 32, 12, 1), 256, 0, stream>>>(Wh, whead_t, EMB, VOC, 0, 0);

  embed_k<<<NTOK, EMB, 0, stream>>>(idx, tok, pos, x);

  for (int l = 0; l < NL; ++l) {
    ln_k<<<NTOK / 4, 256, 0, stream>>>(x, ln1g + l * EMB, ln1b + l * EMB, hb);
    gemm_k<GM_QKV><<<dim3(32, 9), 256, 0, stream>>>(hb, wqkv_t + (size_t)l * QKVW * EMB, qkv,
        nullptr, nullptr, EMB, EMB, EMB, QKVW, 0.f, nullptr, nullptr);
    vtrans_k<<<dim3(4, 96), 256, 0, stream>>>(qkv, vt);
    attn_k<<<dim3(4, 96), 256, 0, stream>>>(qkv, vt, att);
    gemm64_k<<<dim3(64, 6), 256, 0, stream>>>(att, wproj_t + (size_t)l * EMB * EMB, x,
        bp + l * EMB, x, EMB, EMB, EMB, EMB);
    ln_k<<<NTOK / 4, 256, 0, stream>>>(x, ln2g + l * EMB, ln2b + l * EMB, hb);
    gemm_k<GM_FC1><<<dim3(32, 12), 256, 0, stream>>>(hb, w1_t + (size_t)l * FF * EMB, f1,
        b1 + l * FF, nullptr, EMB, EMB, EMB, FF, 0.f, nullptr, nullptr);
    gemm64_k<<<dim3(64, 6), 256, 0, stream>>>(f1, w2_t + (size_t)l * EMB * FF, x,
        b2 + l * EMB, x, FF, FF, FF, EMB);
  }

  ln_k<<<NTOK / 4, 256, 0, stream>>>(x, lnfg, lnfb, hb);
  gemm_k<GM_HEAD><<<dim3(32, NCH), 256, 0, stream>>>(hb, whead_t, (float*)d_out,
      bh, nullptr, EMB, EMB, EMB, VOC, 0.f, pm, ps);
  lsecomb_k<<<NTOK / 4, 256, 0, stream>>>(pm, ps, (const float*)d_out, tgt, rl);
  loss_final_k<<<1, 256, 0, stream>>>(rl, (float*)d_out + (size_t)NTOK * VOC);
}